// Round 1
// baseline (224.113 us; speedup 1.0000x reference)
//
#include <hip/hip_runtime.h>

typedef short bf16x8 __attribute__((ext_vector_type(8)));
typedef float f32x4 __attribute__((ext_vector_type(4)));

__device__ __forceinline__ unsigned short f2bf(float f) {
    unsigned int u = __float_as_uint(f);
    unsigned int r = u + 0x7FFFu + ((u >> 16) & 1u);
    return (unsigned short)(r >> 16);
}

// ---------------- weight prep: f32 row-major -> bf16 fragment-major ----------------
// frag layout: idx = ((nt*KS + ks)*64 + lane)*8 + e  ->  W[k = ks*32 + (lane>>4)*8 + e][n = nt*16 + (lane&15)]
__global__ __launch_bounds__(256) void prep_all(
        const float* __restrict__ uW1, const float* __restrict__ uW2, const float* __restrict__ uW3,
        const float* __restrict__ bW1, const float* __restrict__ bW2, const float* __restrict__ bW3,
        unsigned short* __restrict__ ws) {
    int idx = blockIdx.x * 256 + threadIdx.x;
    const float* W; int Ksrc, Nsrc, ntsh; unsigned short* dst; int li;
    if (idx < 8192)       { W = uW1; Ksrc = 38;  Nsrc = 128; ntsh = 10; dst = ws;         li = idx; }
    else if (idx < 16384) { W = bW1; Ksrc = 44;  Nsrc = 128; ntsh = 10; dst = ws + 8192;  li = idx - 8192; }
    else if (idx < 32768) { W = uW2; Ksrc = 128; Nsrc = 128; ntsh = 11; dst = ws + 16384; li = idx - 16384; }
    else if (idx < 49152) { W = bW2; Ksrc = 128; Nsrc = 128; ntsh = 11; dst = ws + 32768; li = idx - 32768; }
    else if (idx < 51200) { W = uW3; Ksrc = 128; Nsrc = 6;   ntsh = 11; dst = ws + 49152; li = idx - 49152; }
    else if (idx < 53248) { W = bW3; Ksrc = 128; Nsrc = 6;   ntsh = 11; dst = ws + 51200; li = idx - 51200; }
    else return;
    int e  = li & 7;
    int l  = (li >> 3) & 63;
    int KS = (ntsh == 10) ? 2 : 4;
    int ks = (li >> 9) & (KS - 1);
    int nt = li >> ntsh;
    int k  = ks * 32 + (l >> 4) * 8 + e;
    int n  = nt * 16 + (l & 15);
    float v = (k < Ksrc && n < Nsrc) ? W[k * Nsrc + n] : 0.0f;
    dst[li] = f2bf(v);
}

// ---------------- fused MLP kernel ----------------
// BINARY=0: grid 512 blocks, block covers 128 unary rows (row = b*16 + i).
// BINARY=1: grid 8192 blocks (b = blk>>1, h = blk&1), block covers 128 pair-rows (i = h*8+2w+mt, j = row&15).
// Each wave (4/block) owns 32 rows end-to-end; per-wave 8KB LDS buffer reused X -> H1 -> H2.
template <int BINARY>
__global__ __launch_bounds__(256, 4) void mlp_kernel(
        const float* __restrict__ config, const float* __restrict__ action,
        const unsigned short* __restrict__ W1f, const float* __restrict__ b1,
        const unsigned short* __restrict__ W2f, const float* __restrict__ b2,
        const unsigned short* __restrict__ W3f, const float* __restrict__ b3,
        float* __restrict__ out) {
    __shared__ __align__(16) unsigned char smem[4 * 8192];
    const int tid = threadIdx.x;
    const int w = tid >> 6;       // wave 0..3
    const int l = tid & 63;       // lane
    const int g = l >> 4;         // lane group 0..3
    const int c = l & 15;         // low nibble
    unsigned char* buf = smem + w * 8192;

    // ---- build X tile (32 rows x 64 K, bf16, row stride 128B, XOR-swizzled) ----
    {
        const int rowL = l >> 1;                 // 0..31
        const int kh   = l & 1;                  // k half
        const int sw   = (rowL & 7) << 4;
        const int base = rowL * 128 + kh * 64;
        const float* cb; const float* ab; int i, j;
        if constexpr (BINARY) {
            const int b = blockIdx.x >> 1, h = blockIdx.x & 1;
            i = h * 8 + 2 * w + (rowL >> 4);
            j = rowL & 15;
            cb = config + b * 96;
            ab = action + b * 32;
        } else {
            const int rg = blockIdx.x * 128 + w * 32 + rowL;
            const int b = rg >> 4;
            i = rg & 15; j = 0;
            cb = config + b * 96;
            ab = action + b * 32;
        }
        (void)j;
        if (kh == 0) {
            #pragma unroll
            for (int ch = 0; ch < 4; ++ch) {
                bf16x8 v;
                #pragma unroll
                for (int t8 = 0; t8 < 8; ++t8) {
                    const int k = ch * 8 + t8;   // 0..31 (compile-time)
                    float x;
                    if constexpr (BINARY)
                        x = (k < 6) ? cb[i * 6 + k] : (k < 12) ? cb[j * 6 + (k - 6)] : ab[k - 12];
                    else
                        x = (k < 6) ? cb[i * 6 + k] : ab[k - 6];
                    v[t8] = (short)f2bf(x);
                }
                *(bf16x8*)(buf + ((base + ch * 16) ^ sw)) = v;
            }
        } else {
            #pragma unroll
            for (int ch = 0; ch < 4; ++ch) {
                bf16x8 v;
                #pragma unroll
                for (int t8 = 0; t8 < 8; ++t8) {
                    const int k = 32 + ch * 8 + t8;  // 32..63 (compile-time)
                    float x;
                    if constexpr (BINARY)
                        x = (k < 44) ? ab[k - 12] : 0.0f;
                    else
                        x = (k < 38) ? ab[k - 6] : 0.0f;
                    v[t8] = (short)f2bf(x);
                }
                *(bf16x8*)(buf + ((base + ch * 16) ^ sw)) = v;
            }
        }
    }
    __syncthreads();

    const f32x4 zero4 = {0.f, 0.f, 0.f, 0.f};

    // ---- preload X A-fragments (then buf may be overwritten) ----
    bf16x8 xf[2][2];
    #pragma unroll
    for (int mt = 0; mt < 2; ++mt)
        #pragma unroll
        for (int ks = 0; ks < 2; ++ks) {
            const int row = mt * 16 + c;
            xf[mt][ks] = *(const bf16x8*)(buf + ((row * 128 + ks * 64 + g * 16) ^ ((c & 7) << 4)));
        }

    // ---- GEMM1: H1 = relu(X @ W1 + b1), K=64, N=128, written to buf (stride 256B) ----
    #pragma unroll
    for (int nh = 0; nh < 2; ++nh) {
        f32x4 acc[2][4];
        #pragma unroll
        for (int mt = 0; mt < 2; ++mt)
            #pragma unroll
            for (int ntl = 0; ntl < 4; ++ntl) acc[mt][ntl] = zero4;
        #pragma unroll
        for (int ntl = 0; ntl < 4; ++ntl) {
            const int nt = nh * 4 + ntl;
            #pragma unroll
            for (int ks = 0; ks < 2; ++ks) {
                const bf16x8 bfr = *(const bf16x8*)(W1f + ((nt * 2 + ks) * 64 + l) * 8);
                #pragma unroll
                for (int mt = 0; mt < 2; ++mt)
                    acc[mt][ntl] = __builtin_amdgcn_mfma_f32_16x16x32_bf16(xf[mt][ks], bfr, acc[mt][ntl], 0, 0, 0);
            }
        }
        #pragma unroll
        for (int ntl = 0; ntl < 4; ++ntl) {
            const int col = (nh * 4 + ntl) * 16 + c;
            const float bias = b1[col];
            #pragma unroll
            for (int mt = 0; mt < 2; ++mt)
                #pragma unroll
                for (int r = 0; r < 4; ++r) {
                    const int row = mt * 16 + g * 4 + r;
                    const float hv = fmaxf(acc[mt][ntl][r] + bias, 0.f);
                    *(unsigned short*)(buf + ((row * 256 + col * 2) ^ ((row & 7) << 4))) = f2bf(hv);
                }
        }
    }
    __syncthreads();

    // ---- preload H1 A-fragments ----
    bf16x8 hf[2][4];
    #pragma unroll
    for (int mt = 0; mt < 2; ++mt)
        #pragma unroll
        for (int ks = 0; ks < 4; ++ks) {
            const int row = mt * 16 + c;
            hf[mt][ks] = *(const bf16x8*)(buf + ((row * 256 + ks * 64 + g * 16) ^ ((c & 7) << 4)));
        }

    // ---- GEMM2: H2 = relu(H1 @ W2 + b2), K=128, N=128, overwrite buf ----
    #pragma unroll
    for (int nh = 0; nh < 2; ++nh) {
        f32x4 acc[2][4];
        #pragma unroll
        for (int mt = 0; mt < 2; ++mt)
            #pragma unroll
            for (int ntl = 0; ntl < 4; ++ntl) acc[mt][ntl] = zero4;
        #pragma unroll
        for (int ntl = 0; ntl < 4; ++ntl) {
            const int nt = nh * 4 + ntl;
            #pragma unroll
            for (int ks = 0; ks < 4; ++ks) {
                const bf16x8 bfr = *(const bf16x8*)(W2f + ((nt * 4 + ks) * 64 + l) * 8);
                #pragma unroll
                for (int mt = 0; mt < 2; ++mt)
                    acc[mt][ntl] = __builtin_amdgcn_mfma_f32_16x16x32_bf16(hf[mt][ks], bfr, acc[mt][ntl], 0, 0, 0);
            }
        }
        #pragma unroll
        for (int ntl = 0; ntl < 4; ++ntl) {
            const int col = (nh * 4 + ntl) * 16 + c;
            const float bias = b2[col];
            #pragma unroll
            for (int mt = 0; mt < 2; ++mt)
                #pragma unroll
                for (int r = 0; r < 4; ++r) {
                    const int row = mt * 16 + g * 4 + r;
                    const float hv = fmaxf(acc[mt][ntl][r] + bias, 0.f);
                    *(unsigned short*)(buf + ((row * 256 + col * 2) ^ ((row & 7) << 4))) = f2bf(hv);
                }
        }
    }
    __syncthreads();

    // ---- preload H2 A-fragments ----
    bf16x8 h2f[2][4];
    #pragma unroll
    for (int mt = 0; mt < 2; ++mt)
        #pragma unroll
        for (int ks = 0; ks < 4; ++ks) {
            const int row = mt * 16 + c;
            h2f[mt][ks] = *(const bf16x8*)(buf + ((row * 256 + ks * 64 + g * 16) ^ ((c & 7) << 4)));
        }

    // ---- GEMM3: out = H2 @ W3 + b3, K=128, N=16 (cols 6..15 are zero-padded) ----
    f32x4 acc3[2];
    acc3[0] = zero4; acc3[1] = zero4;
    #pragma unroll
    for (int ks = 0; ks < 4; ++ks) {
        const bf16x8 bfr = *(const bf16x8*)(W3f + (ks * 64 + l) * 8);
        #pragma unroll
        for (int mt = 0; mt < 2; ++mt)
            acc3[mt] = __builtin_amdgcn_mfma_f32_16x16x32_bf16(h2f[mt][ks], bfr, acc3[mt], 0, 0, 0);
    }

    // ---- epilogue ----
    if constexpr (BINARY) {
        const int b = blockIdx.x >> 1, h = blockIdx.x & 1;
        const float b3v = (c < 6) ? b3[c] : 0.f;
        #pragma unroll
        for (int mt = 0; mt < 2; ++mt) {
            const int i = h * 8 + 2 * w + mt;
            float s = 0.f;
            #pragma unroll
            for (int r = 0; r < 4; ++r) {
                const int j = g * 4 + r;
                const float v = acc3[mt][r] + b3v;
                if (j != i) s += v;             // mask diagonal
            }
            s += __shfl_xor(s, 16, 64);
            s += __shfl_xor(s, 32, 64);         // all lanes now hold sum over all 16 j
            if (g == 0 && c < 6) {
                float* p = out + b * 96 + i * 6 + c;
                *p += s;                        // unary kernel wrote objs + u_out first
            }
        }
    } else {
        const int rgbase = blockIdx.x * 128 + w * 32;
        const float b3v = (c < 6) ? b3[c] : 0.f;
        #pragma unroll
        for (int mt = 0; mt < 2; ++mt)
            #pragma unroll
            for (int r = 0; r < 4; ++r) {
                const int rg = rgbase + mt * 16 + g * 4 + r;
                const int b = rg >> 4, i = rg & 15;
                if (c < 6) {
                    const int idx = b * 96 + i * 6 + c;
                    out[idx] = acc3[mt][r] + b3v + config[idx];  // objs + u_out
                }
            }
    }
}

extern "C" void kernel_launch(void* const* d_in, const int* in_sizes, int n_in,
                              void* d_out, int out_size, void* d_ws, size_t ws_size,
                              hipStream_t stream) {
    const float* config = (const float*)d_in[0];
    const float* action = (const float*)d_in[1];
    const float* uW1 = (const float*)d_in[2];
    const float* ub1 = (const float*)d_in[3];
    const float* uW2 = (const float*)d_in[4];
    const float* ub2 = (const float*)d_in[5];
    const float* uW3 = (const float*)d_in[6];
    const float* ub3 = (const float*)d_in[7];
    const float* bW1 = (const float*)d_in[8];
    const float* bb1 = (const float*)d_in[9];
    const float* bW2 = (const float*)d_in[10];
    const float* bb2 = (const float*)d_in[11];
    const float* bW3 = (const float*)d_in[12];
    const float* bb3 = (const float*)d_in[13];
    float* out = (float*)d_out;

    unsigned short* ws   = (unsigned short*)d_ws;
    unsigned short* uW1f = ws;            // 8192 elems
    unsigned short* bW1f = ws + 8192;     // 8192
    unsigned short* uW2f = ws + 16384;    // 16384
    unsigned short* bW2f = ws + 32768;    // 16384
    unsigned short* uW3f = ws + 49152;    // 2048
    unsigned short* bW3f = ws + 51200;    // 2048

    prep_all<<<208, 256, 0, stream>>>(uW1, uW2, uW3, bW1, bW2, bW3, ws);
    // unary first: writes out = objs + u_out (every element exactly once)
    mlp_kernel<0><<<512, 256, 0, stream>>>(config, action, uW1f, ub1, uW2f, ub2, uW3f, ub3, out);
    // binary second: out += b_sum (stream-ordered after unary)
    mlp_kernel<1><<<8192, 256, 0, stream>>>(config, action, bW1f, bb1, bW2f, bb2, bW3f, bb3, out);
}

// Round 2
// 179.847 us; speedup vs baseline: 1.2461x; 1.2461x over previous
//
#include <hip/hip_runtime.h>

typedef short bf16x8 __attribute__((ext_vector_type(8)));
typedef float f32x4 __attribute__((ext_vector_type(4)));

__device__ __forceinline__ unsigned short f2bf(float f) {
    unsigned int u = __float_as_uint(f);
    unsigned int r = u + 0x7FFFu + ((u >> 16) & 1u);
    return (unsigned short)(r >> 16);
}

// pack two f32 -> one u32 of 2 bf16 (lo = a, hi = b), single HW instruction
__device__ __forceinline__ unsigned pkbf(float a, float b) {
    unsigned r;
    asm volatile("v_cvt_pk_bf16_f32 %0, %1, %2" : "=v"(r) : "v"(a), "v"(b));
    return r;
}

// ---------------- weight prep: f32 row-major -> bf16 fragment-major ----------------
// frag layout: idx = ((nt*KS + ks)*64 + lane)*8 + e  ->  W[k = ks*32 + (lane>>4)*8 + e][n = nt*16 + (lane&15)]
__global__ __launch_bounds__(256) void prep_all(
        const float* __restrict__ uW1, const float* __restrict__ uW2, const float* __restrict__ uW3,
        const float* __restrict__ bW1, const float* __restrict__ bW2, const float* __restrict__ bW3,
        unsigned short* __restrict__ ws) {
    int idx = blockIdx.x * 256 + threadIdx.x;
    const float* W; int Ksrc, Nsrc, ntsh; unsigned short* dst; int li;
    if (idx < 8192)       { W = uW1; Ksrc = 38;  Nsrc = 128; ntsh = 10; dst = ws;         li = idx; }
    else if (idx < 16384) { W = bW1; Ksrc = 44;  Nsrc = 128; ntsh = 10; dst = ws + 8192;  li = idx - 8192; }
    else if (idx < 32768) { W = uW2; Ksrc = 128; Nsrc = 128; ntsh = 11; dst = ws + 16384; li = idx - 16384; }
    else if (idx < 49152) { W = bW2; Ksrc = 128; Nsrc = 128; ntsh = 11; dst = ws + 32768; li = idx - 32768; }
    else if (idx < 51200) { W = uW3; Ksrc = 128; Nsrc = 6;   ntsh = 11; dst = ws + 49152; li = idx - 49152; }
    else if (idx < 53248) { W = bW3; Ksrc = 128; Nsrc = 6;   ntsh = 11; dst = ws + 51200; li = idx - 51200; }
    else return;
    int e  = li & 7;
    int l  = (li >> 3) & 63;
    int KS = (ntsh == 10) ? 2 : 4;
    int ks = (li >> 9) & (KS - 1);
    int nt = li >> ntsh;
    int k  = ks * 32 + (l >> 4) * 8 + e;
    int n  = nt * 16 + (l & 15);
    float v = (k < Ksrc && n < Nsrc) ? W[k * Nsrc + n] : 0.0f;
    dst[li] = f2bf(v);
}

// ---------------- unary kernel (round-1 structure, relaxed reg bound) ----------------
template <int BINARY>
__global__ __launch_bounds__(256, 3) void mlp_kernel(
        const float* __restrict__ config, const float* __restrict__ action,
        const unsigned short* __restrict__ W1f, const float* __restrict__ b1,
        const unsigned short* __restrict__ W2f, const float* __restrict__ b2,
        const unsigned short* __restrict__ W3f, const float* __restrict__ b3,
        float* __restrict__ out) {
    __shared__ __align__(16) unsigned char smem[4 * 8192];
    const int tid = threadIdx.x;
    const int w = tid >> 6;
    const int l = tid & 63;
    const int g = l >> 4;
    const int c = l & 15;
    unsigned char* buf = smem + w * 8192;

    // ---- build X tile (32 rows x 64 K, bf16, row stride 128B, XOR-swizzled) ----
    {
        const int rowL = l >> 1;
        const int kh   = l & 1;
        const int sw   = (rowL & 7) << 4;
        const int base = rowL * 128 + kh * 64;
        const int rg = blockIdx.x * 128 + w * 32 + rowL;
        const int b = rg >> 4;
        const int i = rg & 15;
        const float* cb = config + b * 96;
        const float* ab = action + b * 32;
        if (kh == 0) {
            #pragma unroll
            for (int ch = 0; ch < 4; ++ch) {
                bf16x8 v;
                #pragma unroll
                for (int t8 = 0; t8 < 8; ++t8) {
                    const int k = ch * 8 + t8;
                    float x = (k < 6) ? cb[i * 6 + k] : ab[k - 6];
                    v[t8] = (short)f2bf(x);
                }
                *(bf16x8*)(buf + ((base + ch * 16) ^ sw)) = v;
            }
        } else {
            #pragma unroll
            for (int ch = 0; ch < 4; ++ch) {
                bf16x8 v;
                #pragma unroll
                for (int t8 = 0; t8 < 8; ++t8) {
                    const int k = 32 + ch * 8 + t8;
                    float x = (k < 38) ? ab[k - 6] : 0.0f;
                    v[t8] = (short)f2bf(x);
                }
                *(bf16x8*)(buf + ((base + ch * 16) ^ sw)) = v;
            }
        }
    }
    __syncthreads();

    const f32x4 zero4 = {0.f, 0.f, 0.f, 0.f};

    bf16x8 xf[2][2];
    #pragma unroll
    for (int mt = 0; mt < 2; ++mt)
        #pragma unroll
        for (int ks = 0; ks < 2; ++ks) {
            const int row = mt * 16 + c;
            xf[mt][ks] = *(const bf16x8*)(buf + ((row * 128 + ks * 64 + g * 16) ^ ((c & 7) << 4)));
        }

    // GEMM1
    #pragma unroll
    for (int nh = 0; nh < 2; ++nh) {
        f32x4 acc[2][4];
        #pragma unroll
        for (int mt = 0; mt < 2; ++mt)
            #pragma unroll
            for (int ntl = 0; ntl < 4; ++ntl) acc[mt][ntl] = zero4;
        #pragma unroll
        for (int ntl = 0; ntl < 4; ++ntl) {
            const int nt = nh * 4 + ntl;
            #pragma unroll
            for (int ks = 0; ks < 2; ++ks) {
                const bf16x8 bfr = *(const bf16x8*)(W1f + ((nt * 2 + ks) * 64 + l) * 8);
                #pragma unroll
                for (int mt = 0; mt < 2; ++mt)
                    acc[mt][ntl] = __builtin_amdgcn_mfma_f32_16x16x32_bf16(xf[mt][ks], bfr, acc[mt][ntl], 0, 0, 0);
            }
        }
        #pragma unroll
        for (int ntl = 0; ntl < 4; ++ntl) {
            const int col = (nh * 4 + ntl) * 16 + c;
            const float bias = b1[col];
            #pragma unroll
            for (int mt = 0; mt < 2; ++mt)
                #pragma unroll
                for (int r = 0; r < 4; ++r) {
                    const int row = mt * 16 + g * 4 + r;
                    const float hv = fmaxf(acc[mt][ntl][r] + bias, 0.f);
                    *(unsigned short*)(buf + ((row * 256 + col * 2) ^ ((row & 7) << 4))) = f2bf(hv);
                }
        }
    }
    __syncthreads();

    bf16x8 hf[2][4];
    #pragma unroll
    for (int mt = 0; mt < 2; ++mt)
        #pragma unroll
        for (int ks = 0; ks < 4; ++ks) {
            const int row = mt * 16 + c;
            hf[mt][ks] = *(const bf16x8*)(buf + ((row * 256 + ks * 64 + g * 16) ^ ((c & 7) << 4)));
        }

    // GEMM2
    #pragma unroll
    for (int nh = 0; nh < 2; ++nh) {
        f32x4 acc[2][4];
        #pragma unroll
        for (int mt = 0; mt < 2; ++mt)
            #pragma unroll
            for (int ntl = 0; ntl < 4; ++ntl) acc[mt][ntl] = zero4;
        #pragma unroll
        for (int ntl = 0; ntl < 4; ++ntl) {
            const int nt = nh * 4 + ntl;
            #pragma unroll
            for (int ks = 0; ks < 4; ++ks) {
                const bf16x8 bfr = *(const bf16x8*)(W2f + ((nt * 4 + ks) * 64 + l) * 8);
                #pragma unroll
                for (int mt = 0; mt < 2; ++mt)
                    acc[mt][ntl] = __builtin_amdgcn_mfma_f32_16x16x32_bf16(hf[mt][ks], bfr, acc[mt][ntl], 0, 0, 0);
            }
        }
        #pragma unroll
        for (int ntl = 0; ntl < 4; ++ntl) {
            const int col = (nh * 4 + ntl) * 16 + c;
            const float bias = b2[col];
            #pragma unroll
            for (int mt = 0; mt < 2; ++mt)
                #pragma unroll
                for (int r = 0; r < 4; ++r) {
                    const int row = mt * 16 + g * 4 + r;
                    const float hv = fmaxf(acc[mt][ntl][r] + bias, 0.f);
                    *(unsigned short*)(buf + ((row * 256 + col * 2) ^ ((row & 7) << 4))) = f2bf(hv);
                }
        }
    }
    __syncthreads();

    bf16x8 h2f[2][4];
    #pragma unroll
    for (int mt = 0; mt < 2; ++mt)
        #pragma unroll
        for (int ks = 0; ks < 4; ++ks) {
            const int row = mt * 16 + c;
            h2f[mt][ks] = *(const bf16x8*)(buf + ((row * 256 + ks * 64 + g * 16) ^ ((c & 7) << 4)));
        }

    // GEMM3
    f32x4 acc3[2];
    acc3[0] = zero4; acc3[1] = zero4;
    #pragma unroll
    for (int ks = 0; ks < 4; ++ks) {
        const bf16x8 bfr = *(const bf16x8*)(W3f + (ks * 64 + l) * 8);
        #pragma unroll
        for (int mt = 0; mt < 2; ++mt)
            acc3[mt] = __builtin_amdgcn_mfma_f32_16x16x32_bf16(h2f[mt][ks], bfr, acc3[mt], 0, 0, 0);
    }

    const int rgbase = blockIdx.x * 128 + w * 32;
    const float b3v = (c < 6) ? b3[c] : 0.f;
    #pragma unroll
    for (int mt = 0; mt < 2; ++mt)
        #pragma unroll
        for (int r = 0; r < 4; ++r) {
            const int rg = rgbase + mt * 16 + g * 4 + r;
            const int b = rg >> 4, i = rg & 15;
            if (c < 6) {
                const int idx = b * 96 + i * 6 + c;
                out[idx] = acc3[mt][r] + b3v + config[idx];
            }
        }
}

// ---------------- binary kernel: H1[i,j] = relu(P'[i] + Q[j]) decomposition ----------------
// grid 8192: b = blk>>1, h = blk&1. Block covers i in [8h, 8h+8), all j.
// Wave w owns prows p = c + 16*nt  ->  (i = 8h+2w+nt, j = c).
__global__ __launch_bounds__(256, 3) void binary_kernel(
        const float* __restrict__ config, const float* __restrict__ action,
        const unsigned short* __restrict__ W1f, const float* __restrict__ b1,
        const unsigned short* __restrict__ W2f, const float* __restrict__ b2,
        const unsigned short* __restrict__ W3f, const float* __restrict__ b3,
        float* __restrict__ out) {
    __shared__ __align__(16) unsigned char Ts[4096];     // T: 32 x 64 bf16, swizzled
    __shared__ __align__(16) unsigned char PQs[16384];   // P'/Q: 32 x 128 f32, swizzled
    __shared__ __align__(16) unsigned char H2s[32768];   // per-wave 8KB: H2 32 x 128 bf16

    const int tid = threadIdx.x;
    const int w = tid >> 6, l = tid & 63, g = l >> 4, c = l & 15;
    const int b = blockIdx.x >> 1, h = blockIdx.x & 1;
    const float* cb = config + b * 96;
    const float* ab = action + b * 32;
    const f32x4 zero4 = {0.f, 0.f, 0.f, 0.f};

    // ---- phase 0: build T. rows 0-15: [obj_i | 0 | action | 0], rows 16-31: [0 | obj_j | 0] ----
    {
        const int p  = tid >> 3;          // 0..31
        const int k0 = (tid & 7) * 8;     // 0..56
        union { unsigned short us[8]; bf16x8 v; } u;
        #pragma unroll
        for (int e = 0; e < 8; ++e) {
            const int k = k0 + e;
            float x = 0.f;
            if (p < 16) {
                if (k < 6) x = cb[p * 6 + k];
                else if (k >= 12 && k < 44) x = ab[k - 12];
            } else {
                if (k >= 6 && k < 12) x = cb[(p - 16) * 6 + (k - 6)];
            }
            u.us[e] = f2bf(x);
        }
        *(bf16x8*)(Ts + ((p * 128 + k0 * 2) ^ ((p & 7) << 4))) = u.v;
    }
    __syncthreads();

    // ---- phase 1: T-GEMM -> PQ.  [P'+b1 ; Q] = T @ W1 (M=32, N=128, K=64), wave w does nt=2w,2w+1 ----
    {
        bf16x8 afr[2][2];
        #pragma unroll
        for (int mt = 0; mt < 2; ++mt)
            #pragma unroll
            for (int ks = 0; ks < 2; ++ks)
                afr[mt][ks] = *(const bf16x8*)(Ts + (((c + 16 * mt) * 128 + 64 * ks + 16 * g) ^ ((c & 7) << 4)));
        f32x4 acc[2][2];
        acc[0][0] = zero4; acc[0][1] = zero4; acc[1][0] = zero4; acc[1][1] = zero4;
        #pragma unroll
        for (int ntl = 0; ntl < 2; ++ntl) {
            const int nt = 2 * w + ntl;
            #pragma unroll
            for (int ks = 0; ks < 2; ++ks) {
                const bf16x8 bfr = *(const bf16x8*)(W1f + ((nt * 2 + ks) * 64 + l) * 8);
                #pragma unroll
                for (int mt = 0; mt < 2; ++mt)
                    acc[mt][ntl] = __builtin_amdgcn_mfma_f32_16x16x32_bf16(afr[mt][ks], bfr, acc[mt][ntl], 0, 0, 0);
            }
        }
        #pragma unroll
        for (int ntl = 0; ntl < 2; ++ntl) {
            const int f = (2 * w + ntl) * 16 + c;
            const float bias = b1[f];
            #pragma unroll
            for (int mt = 0; mt < 2; ++mt)
                #pragma unroll
                for (int r = 0; r < 4; ++r) {
                    const int row = 16 * mt + 4 * g + r;
                    const float v = acc[mt][ntl][r] + (mt == 0 ? bias : 0.f);
                    *(float*)(PQs + ((row * 512 + f * 4) ^ ((row & 7) << 4))) = v;
                }
        }
    }
    __syncthreads();

    // ---- phase 2: H1 B-fragments in registers: relu(P'[i] + Q[c]) ----
    const int i0 = h * 8 + 2 * w;
    bf16x8 h1f[2][4];
    #pragma unroll
    for (int nt = 0; nt < 2; ++nt) {
        const int i = i0 + nt;
        #pragma unroll
        for (int ks = 0; ks < 4; ++ks) {
            const int kb = (32 * ks + 8 * g) * 4;
            const f32x4 p0 = *(const f32x4*)(PQs + ((i * 512 + kb) ^ ((i & 7) << 4)));
            const f32x4 p1 = *(const f32x4*)(PQs + ((i * 512 + kb + 16) ^ ((i & 7) << 4)));
            const f32x4 q0 = *(const f32x4*)(PQs + (((16 + c) * 512 + kb) ^ ((c & 7) << 4)));
            const f32x4 q1 = *(const f32x4*)(PQs + (((16 + c) * 512 + kb + 16) ^ ((c & 7) << 4)));
            union { unsigned u[4]; bf16x8 v; } un;
            un.u[0] = pkbf(fmaxf(p0[0] + q0[0], 0.f), fmaxf(p0[1] + q0[1], 0.f));
            un.u[1] = pkbf(fmaxf(p0[2] + q0[2], 0.f), fmaxf(p0[3] + q0[3], 0.f));
            un.u[2] = pkbf(fmaxf(p1[0] + q1[0], 0.f), fmaxf(p1[1] + q1[1], 0.f));
            un.u[3] = pkbf(fmaxf(p1[2] + q1[2], 0.f), fmaxf(p1[3] + q1[3], 0.f));
            h1f[nt][ks] = un.v;
        }
    }

    // ---- phase 3: swapped GEMM2: H2^T = W2^T @ H1^T  (A-frag(W2^T) == prepped B-frag(W2)) ----
    f32x4 acc2[8][2];
    #pragma unroll
    for (int mt = 0; mt < 8; ++mt) { acc2[mt][0] = zero4; acc2[mt][1] = zero4; }
    #pragma unroll
    for (int mt = 0; mt < 8; ++mt) {
        #pragma unroll
        for (int ks = 0; ks < 4; ++ks) {
            const bf16x8 wf = *(const bf16x8*)(W2f + ((mt * 4 + ks) * 64 + l) * 8);
            acc2[mt][0] = __builtin_amdgcn_mfma_f32_16x16x32_bf16(wf, h1f[0][ks], acc2[mt][0], 0, 0, 0);
            acc2[mt][1] = __builtin_amdgcn_mfma_f32_16x16x32_bf16(wf, h1f[1][ks], acc2[mt][1], 0, 0, 0);
        }
    }

    // ---- phase 4: H2 -> per-wave LDS, packed b64 writes along mu (bias+relu fused) ----
    unsigned char* Hw = H2s + w * 8192;
    #pragma unroll
    for (int mt = 0; mt < 8; ++mt) {
        const f32x4 bv = *(const f32x4*)(b2 + 16 * mt + 4 * g);
        #pragma unroll
        for (int nt = 0; nt < 2; ++nt) {
            const int p = c + 16 * nt;
            uint2 pk2;
            pk2.x = pkbf(fmaxf(acc2[mt][nt][0] + bv[0], 0.f), fmaxf(acc2[mt][nt][1] + bv[1], 0.f));
            pk2.y = pkbf(fmaxf(acc2[mt][nt][2] + bv[2], 0.f), fmaxf(acc2[mt][nt][3] + bv[3], 0.f));
            *(uint2*)(Hw + ((p * 256 + 32 * mt + 8 * g) ^ ((c & 7) << 4))) = pk2;
        }
    }
    // per-wave region: no block barrier needed (compiler orders ds_write->ds_read)

    // ---- phase 5: GEMM3: out = H2 @ W3 ----
    f32x4 acc3[2];
    acc3[0] = zero4; acc3[1] = zero4;
    #pragma unroll
    for (int ks = 0; ks < 4; ++ks) {
        const bf16x8 w3 = *(const bf16x8*)(W3f + (ks * 64 + l) * 8);
        #pragma unroll
        for (int mtA = 0; mtA < 2; ++mtA) {
            const bf16x8 hfr = *(const bf16x8*)(Hw + (((c + 16 * mtA) * 256 + 64 * ks + 16 * g) ^ ((c & 7) << 4)));
            acc3[mtA] = __builtin_amdgcn_mfma_f32_16x16x32_bf16(hfr, w3, acc3[mtA], 0, 0, 0);
        }
    }

    // ---- phase 6: mask diagonal, sum over j, accumulate into out ----
    const float b3v = (c < 6) ? b3[c] : 0.f;
    #pragma unroll
    for (int mt = 0; mt < 2; ++mt) {
        const int i = i0 + mt;
        float s = 0.f;
        #pragma unroll
        for (int r = 0; r < 4; ++r) {
            const int j = 4 * g + r;
            if (j != i) s += acc3[mt][r] + b3v;
        }
        s += __shfl_xor(s, 16, 64);
        s += __shfl_xor(s, 32, 64);
        if (g == 0 && c < 6) out[b * 96 + i * 6 + c] += s;
    }
}

extern "C" void kernel_launch(void* const* d_in, const int* in_sizes, int n_in,
                              void* d_out, int out_size, void* d_ws, size_t ws_size,
                              hipStream_t stream) {
    const float* config = (const float*)d_in[0];
    const float* action = (const float*)d_in[1];
    const float* uW1 = (const float*)d_in[2];
    const float* ub1 = (const float*)d_in[3];
    const float* uW2 = (const float*)d_in[4];
    const float* ub2 = (const float*)d_in[5];
    const float* uW3 = (const float*)d_in[6];
    const float* ub3 = (const float*)d_in[7];
    const float* bW1 = (const float*)d_in[8];
    const float* bb1 = (const float*)d_in[9];
    const float* bW2 = (const float*)d_in[10];
    const float* bb2 = (const float*)d_in[11];
    const float* bW3 = (const float*)d_in[12];
    const float* bb3 = (const float*)d_in[13];
    float* out = (float*)d_out;

    unsigned short* ws   = (unsigned short*)d_ws;
    unsigned short* uW1f = ws;            // 8192 elems
    unsigned short* bW1f = ws + 8192;     // 8192
    unsigned short* uW2f = ws + 16384;    // 16384
    unsigned short* bW2f = ws + 32768;    // 16384
    unsigned short* uW3f = ws + 49152;    // 2048
    unsigned short* bW3f = ws + 51200;    // 2048

    prep_all<<<208, 256, 0, stream>>>(uW1, uW2, uW3, bW1, bW2, bW3, ws);
    // unary first: writes out = objs + u_out (every element exactly once)
    mlp_kernel<0><<<512, 256, 0, stream>>>(config, action, uW1f, ub1, uW2f, ub2, uW3f, ub3, out);
    // binary second: out += b_sum (stream-ordered after unary)
    binary_kernel<<<8192, 256, 0, stream>>>(config, action, bW1f, bb1, bW2f, bb2, bW3f, bb3, out);
}

// Round 3
// 163.785 us; speedup vs baseline: 1.3683x; 1.0981x over previous
//
#include <hip/hip_runtime.h>

typedef short bf16x8 __attribute__((ext_vector_type(8)));
typedef float f32x4 __attribute__((ext_vector_type(4)));

__device__ __forceinline__ unsigned short f2bf(float f) {
    unsigned int u = __float_as_uint(f);
    unsigned int r = u + 0x7FFFu + ((u >> 16) & 1u);
    return (unsigned short)(r >> 16);
}

// pack two f32 -> one u32 of 2 bf16 (lo = a, hi = b)
__device__ __forceinline__ unsigned pkbf(float a, float b) {
    unsigned r;
    asm volatile("v_cvt_pk_bf16_f32 %0, %1, %2" : "=v"(r) : "v"(a), "v"(b));
    return r;
}

// ---------------- weight prep: f32 row-major -> bf16 fragment-major ----------------
// frag layout: idx = ((nt*KS + ks)*64 + lane)*8 + e  ->  W[k = ks*32 + (lane>>4)*8 + e][n = nt*16 + (lane&15)]
__global__ __launch_bounds__(256) void prep_all(
        const float* __restrict__ uW1, const float* __restrict__ uW2, const float* __restrict__ uW3,
        const float* __restrict__ bW1, const float* __restrict__ bW2, const float* __restrict__ bW3,
        unsigned short* __restrict__ ws) {
    int idx = blockIdx.x * 256 + threadIdx.x;
    const float* W; int Ksrc, Nsrc, ntsh; unsigned short* dst; int li;
    if (idx < 8192)       { W = uW1; Ksrc = 38;  Nsrc = 128; ntsh = 10; dst = ws;         li = idx; }
    else if (idx < 16384) { W = bW1; Ksrc = 44;  Nsrc = 128; ntsh = 10; dst = ws + 8192;  li = idx - 8192; }
    else if (idx < 32768) { W = uW2; Ksrc = 128; Nsrc = 128; ntsh = 11; dst = ws + 16384; li = idx - 16384; }
    else if (idx < 49152) { W = bW2; Ksrc = 128; Nsrc = 128; ntsh = 11; dst = ws + 32768; li = idx - 32768; }
    else if (idx < 51200) { W = uW3; Ksrc = 128; Nsrc = 6;   ntsh = 11; dst = ws + 49152; li = idx - 49152; }
    else if (idx < 53248) { W = bW3; Ksrc = 128; Nsrc = 6;   ntsh = 11; dst = ws + 51200; li = idx - 51200; }
    else return;
    int e  = li & 7;
    int l  = (li >> 3) & 63;
    int KS = (ntsh == 10) ? 2 : 4;
    int ks = (li >> 9) & (KS - 1);
    int nt = li >> ntsh;
    int k  = ks * 32 + (l >> 4) * 8 + e;
    int n  = nt * 16 + (l & 15);
    float v = (k < Ksrc && n < Nsrc) ? W[k * Nsrc + n] : 0.0f;
    dst[li] = f2bf(v);
}

// ---------------- unary kernel (round-2 structure, vectorized X-build) ----------------
__global__ __launch_bounds__(256, 3) void unary_kernel(
        const float* __restrict__ config, const float* __restrict__ action,
        const unsigned short* __restrict__ W1f, const float* __restrict__ b1,
        const unsigned short* __restrict__ W2f, const float* __restrict__ b2,
        const unsigned short* __restrict__ W3f, const float* __restrict__ b3,
        float* __restrict__ out) {
    __shared__ __align__(16) unsigned char smem[4 * 8192];
    const int tid = threadIdx.x;
    const int w = tid >> 6;
    const int l = tid & 63;
    const int g = l >> 4;
    const int c = l & 15;
    unsigned char* buf = smem + w * 8192;

    // ---- build X tile (32 rows x 64 K, bf16, row stride 128B, XOR-swizzled), vector loads ----
    {
        const int rowL = l >> 1;
        const int kh   = l & 1;
        const int sw   = (rowL & 7) << 4;
        const int base = rowL * 128 + kh * 64;
        const int rg = blockIdx.x * 128 + w * 32 + rowL;
        const int b = rg >> 4;
        const int i = rg & 15;
        const float* cbr = config + b * 96 + i * 6;
        const float* ab  = action + b * 32;
        if (kh == 0) {
            float ov[6];
            { const float2 t0 = *(const float2*)(cbr);
              const float2 t1 = *(const float2*)(cbr + 2);
              const float2 t2 = *(const float2*)(cbr + 4);
              ov[0]=t0.x; ov[1]=t0.y; ov[2]=t1.x; ov[3]=t1.y; ov[4]=t2.x; ov[5]=t2.y; }
            float av[26];
            #pragma unroll
            for (int q = 0; q < 6; ++q) {
                const float4 t = *(const float4*)(ab + 4 * q);
                av[4*q]=t.x; av[4*q+1]=t.y; av[4*q+2]=t.z; av[4*q+3]=t.w;
            }
            { const float2 t = *(const float2*)(ab + 24); av[24]=t.x; av[25]=t.y; }
            #pragma unroll
            for (int ch = 0; ch < 4; ++ch) {
                float x[8];
                #pragma unroll
                for (int t8 = 0; t8 < 8; ++t8) {
                    const int k = ch * 8 + t8;
                    x[t8] = (k < 6) ? ov[k] : av[k - 6];
                }
                union { unsigned uu[4]; bf16x8 v; } U;
                U.uu[0] = pkbf(x[0], x[1]); U.uu[1] = pkbf(x[2], x[3]);
                U.uu[2] = pkbf(x[4], x[5]); U.uu[3] = pkbf(x[6], x[7]);
                *(bf16x8*)(buf + ((base + ch * 16) ^ sw)) = U.v;
            }
        } else {
            float av2[6];
            { const float2 t = *(const float2*)(ab + 26); av2[0]=t.x; av2[1]=t.y; }
            { const float4 t = *(const float4*)(ab + 28); av2[2]=t.x; av2[3]=t.y; av2[4]=t.z; av2[5]=t.w; }
            {
                union { unsigned uu[4]; bf16x8 v; } U;
                U.uu[0] = pkbf(av2[0], av2[1]); U.uu[1] = pkbf(av2[2], av2[3]);
                U.uu[2] = pkbf(av2[4], av2[5]); U.uu[3] = 0u;
                *(bf16x8*)(buf + ((base + 0) ^ sw)) = U.v;
            }
            const bf16x8 z = {0,0,0,0,0,0,0,0};
            *(bf16x8*)(buf + ((base + 16) ^ sw)) = z;
            *(bf16x8*)(buf + ((base + 32) ^ sw)) = z;
            *(bf16x8*)(buf + ((base + 48) ^ sw)) = z;
        }
    }
    __syncthreads();

    const f32x4 zero4 = {0.f, 0.f, 0.f, 0.f};

    bf16x8 xf[2][2];
    #pragma unroll
    for (int mt = 0; mt < 2; ++mt)
        #pragma unroll
        for (int ks = 0; ks < 2; ++ks) {
            const int row = mt * 16 + c;
            xf[mt][ks] = *(const bf16x8*)(buf + ((row * 128 + ks * 64 + g * 16) ^ ((c & 7) << 4)));
        }

    // GEMM1
    #pragma unroll
    for (int nh = 0; nh < 2; ++nh) {
        f32x4 acc[2][4];
        #pragma unroll
        for (int mt = 0; mt < 2; ++mt)
            #pragma unroll
            for (int ntl = 0; ntl < 4; ++ntl) acc[mt][ntl] = zero4;
        #pragma unroll
        for (int ntl = 0; ntl < 4; ++ntl) {
            const int nt = nh * 4 + ntl;
            #pragma unroll
            for (int ks = 0; ks < 2; ++ks) {
                const bf16x8 bfr = *(const bf16x8*)(W1f + ((nt * 2 + ks) * 64 + l) * 8);
                #pragma unroll
                for (int mt = 0; mt < 2; ++mt)
                    acc[mt][ntl] = __builtin_amdgcn_mfma_f32_16x16x32_bf16(xf[mt][ks], bfr, acc[mt][ntl], 0, 0, 0);
            }
        }
        #pragma unroll
        for (int ntl = 0; ntl < 4; ++ntl) {
            const int col = (nh * 4 + ntl) * 16 + c;
            const float bias = b1[col];
            #pragma unroll
            for (int mt = 0; mt < 2; ++mt)
                #pragma unroll
                for (int r = 0; r < 4; ++r) {
                    const int row = mt * 16 + g * 4 + r;
                    const float hv = fmaxf(acc[mt][ntl][r] + bias, 0.f);
                    *(unsigned short*)(buf + ((row * 256 + col * 2) ^ ((row & 7) << 4))) = f2bf(hv);
                }
        }
    }
    __syncthreads();

    bf16x8 hf[2][4];
    #pragma unroll
    for (int mt = 0; mt < 2; ++mt)
        #pragma unroll
        for (int ks = 0; ks < 4; ++ks) {
            const int row = mt * 16 + c;
            hf[mt][ks] = *(const bf16x8*)(buf + ((row * 256 + ks * 64 + g * 16) ^ ((c & 7) << 4)));
        }

    // GEMM2
    #pragma unroll
    for (int nh = 0; nh < 2; ++nh) {
        f32x4 acc[2][4];
        #pragma unroll
        for (int mt = 0; mt < 2; ++mt)
            #pragma unroll
            for (int ntl = 0; ntl < 4; ++ntl) acc[mt][ntl] = zero4;
        #pragma unroll
        for (int ntl = 0; ntl < 4; ++ntl) {
            const int nt = nh * 4 + ntl;
            #pragma unroll
            for (int ks = 0; ks < 4; ++ks) {
                const bf16x8 bfr = *(const bf16x8*)(W2f + ((nt * 4 + ks) * 64 + l) * 8);
                #pragma unroll
                for (int mt = 0; mt < 2; ++mt)
                    acc[mt][ntl] = __builtin_amdgcn_mfma_f32_16x16x32_bf16(hf[mt][ks], bfr, acc[mt][ntl], 0, 0, 0);
            }
        }
        #pragma unroll
        for (int ntl = 0; ntl < 4; ++ntl) {
            const int col = (nh * 4 + ntl) * 16 + c;
            const float bias = b2[col];
            #pragma unroll
            for (int mt = 0; mt < 2; ++mt)
                #pragma unroll
                for (int r = 0; r < 4; ++r) {
                    const int row = mt * 16 + g * 4 + r;
                    const float hv = fmaxf(acc[mt][ntl][r] + bias, 0.f);
                    *(unsigned short*)(buf + ((row * 256 + col * 2) ^ ((row & 7) << 4))) = f2bf(hv);
                }
        }
    }
    __syncthreads();

    bf16x8 h2f[2][4];
    #pragma unroll
    for (int mt = 0; mt < 2; ++mt)
        #pragma unroll
        for (int ks = 0; ks < 4; ++ks) {
            const int row = mt * 16 + c;
            h2f[mt][ks] = *(const bf16x8*)(buf + ((row * 256 + ks * 64 + g * 16) ^ ((c & 7) << 4)));
        }

    // GEMM3
    f32x4 acc3[2];
    acc3[0] = zero4; acc3[1] = zero4;
    #pragma unroll
    for (int ks = 0; ks < 4; ++ks) {
        const bf16x8 bfr = *(const bf16x8*)(W3f + (ks * 64 + l) * 8);
        #pragma unroll
        for (int mt = 0; mt < 2; ++mt)
            acc3[mt] = __builtin_amdgcn_mfma_f32_16x16x32_bf16(h2f[mt][ks], bfr, acc3[mt], 0, 0, 0);
    }

    const int rgbase = blockIdx.x * 128 + w * 32;
    const float b3v = (c < 6) ? b3[c] : 0.f;
    #pragma unroll
    for (int mt = 0; mt < 2; ++mt)
        #pragma unroll
        for (int r = 0; r < 4; ++r) {
            const int rg = rgbase + mt * 16 + g * 4 + r;
            const int b = rg >> 4, i = rg & 15;
            if (c < 6) {
                const int idx = b * 96 + i * 6 + c;
                out[idx] = acc3[mt][r] + b3v + config[idx];
            }
        }
}

// ---------------- binary kernel: chunked H1[i,j] = relu(P'[i] + Q[j]) ----------------
// grid 8192: b = blk>>1, h = blk&1. Block covers i in [8h, 8h+8), all j.
// Wave w owns p-rows p = c + 16*nt  ->  (i = 8h+2w+nt, j = c).
__global__ __launch_bounds__(256, 4) void binary_kernel(
        const float* __restrict__ config, const float* __restrict__ action,
        const unsigned short* __restrict__ W1f, const float* __restrict__ b1,
        const unsigned short* __restrict__ W2f, const float* __restrict__ b2,
        const unsigned short* __restrict__ W3f, const float* __restrict__ b3,
        float* __restrict__ out) {
    __shared__ __align__(16) unsigned char Ts[4096];     // T: 32 x 64 bf16, swizzled
    __shared__ __align__(16) unsigned char PQs[16384];   // P'/Q: 32 x 128 f32, swizzled
    __shared__ __align__(16) unsigned char Cks[8192];    // per-wave 2KB H2 kappa-chunk (32p x 32k bf16)

    const int tid = threadIdx.x;
    const int w = tid >> 6, l = tid & 63, g = l >> 4, c = l & 15;
    const int b = blockIdx.x >> 1, h = blockIdx.x & 1;
    const float* cb = config + b * 96;
    const float* ab = action + b * 32;
    const f32x4 zero4 = {0.f, 0.f, 0.f, 0.f};

    // ---- phase 0: build T. rows 0-15: [obj_i | 0 | action | 0], rows 16-31: [0 | obj_j | 0] ----
    {
        const int p  = tid >> 3;          // 0..31
        const int k0 = (tid & 7) * 8;     // 0..56
        union { unsigned short us[8]; bf16x8 v; } u;
        #pragma unroll
        for (int e = 0; e < 8; ++e) {
            const int k = k0 + e;
            float x = 0.f;
            if (p < 16) {
                if (k < 6) x = cb[p * 6 + k];
                else if (k >= 12 && k < 44) x = ab[k - 12];
            } else {
                if (k >= 6 && k < 12) x = cb[(p - 16) * 6 + (k - 6)];
            }
            u.us[e] = f2bf(x);
        }
        *(bf16x8*)(Ts + ((p * 128 + k0 * 2) ^ ((p & 7) << 4))) = u.v;
    }
    __syncthreads();

    // ---- phase 1 (swapped): PQ^T = W1^T @ T^T; packed b64 writes along f ----
    {
        bf16x8 tfr[2][2];
        #pragma unroll
        for (int nt = 0; nt < 2; ++nt)
            #pragma unroll
            for (int ks = 0; ks < 2; ++ks)
                tfr[nt][ks] = *(const bf16x8*)(Ts + (((c + 16 * nt) * 128 + 64 * ks + 16 * g) ^ ((c & 7) << 4)));
        f32x4 acc1[2][2];
        acc1[0][0] = zero4; acc1[0][1] = zero4; acc1[1][0] = zero4; acc1[1][1] = zero4;
        #pragma unroll
        for (int mt1 = 0; mt1 < 2; ++mt1) {
            #pragma unroll
            for (int ks = 0; ks < 2; ++ks) {
                const bf16x8 wfr = *(const bf16x8*)(W1f + (((2 * w + mt1) * 2 + ks) * 64 + l) * 8);
                acc1[mt1][0] = __builtin_amdgcn_mfma_f32_16x16x32_bf16(wfr, tfr[0][ks], acc1[mt1][0], 0, 0, 0);
                acc1[mt1][1] = __builtin_amdgcn_mfma_f32_16x16x32_bf16(wfr, tfr[1][ks], acc1[mt1][1], 0, 0, 0);
            }
        }
        #pragma unroll
        for (int mt1 = 0; mt1 < 2; ++mt1) {
            const f32x4 bv = *(const f32x4*)(b1 + 32 * w + 16 * mt1 + 4 * g);
            acc1[mt1][0] = acc1[mt1][0] + bv;   // bias only on P rows (nt==0)
            #pragma unroll
            for (int nt = 0; nt < 2; ++nt) {
                const int p = c + 16 * nt;
                const int fb = (32 * w + 16 * mt1 + 4 * g) * 4;   // byte offset of f
                float2 v0; v0.x = acc1[mt1][nt][0]; v0.y = acc1[mt1][nt][1];
                float2 v1; v1.x = acc1[mt1][nt][2]; v1.y = acc1[mt1][nt][3];
                *(float2*)(PQs + ((p * 512 + fb)     ^ ((p & 7) << 4))) = v0;
                *(float2*)(PQs + ((p * 512 + fb + 8) ^ ((p & 7) << 4))) = v1;
            }
        }
    }
    __syncthreads();

    // ---- phase 2: H1 B-fragments in registers: relu(P'[i] + Q[c]) ----
    const int i0 = h * 8 + 2 * w;
    bf16x8 h1f[2][4];
    #pragma unroll
    for (int nt = 0; nt < 2; ++nt) {
        const int i = i0 + nt;
        #pragma unroll
        for (int ks = 0; ks < 4; ++ks) {
            const int kb = (32 * ks + 8 * g) * 4;
            const f32x4 p0 = *(const f32x4*)(PQs + ((i * 512 + kb) ^ ((i & 7) << 4)));
            const f32x4 p1 = *(const f32x4*)(PQs + ((i * 512 + kb + 16) ^ ((i & 7) << 4)));
            const f32x4 q0 = *(const f32x4*)(PQs + (((16 + c) * 512 + kb) ^ ((c & 7) << 4)));
            const f32x4 q1 = *(const f32x4*)(PQs + (((16 + c) * 512 + kb + 16) ^ ((c & 7) << 4)));
            union { unsigned u[4]; bf16x8 v; } un;
            un.u[0] = pkbf(fmaxf(p0[0] + q0[0], 0.f), fmaxf(p0[1] + q0[1], 0.f));
            un.u[1] = pkbf(fmaxf(p0[2] + q0[2], 0.f), fmaxf(p0[3] + q0[3], 0.f));
            un.u[2] = pkbf(fmaxf(p1[0] + q1[0], 0.f), fmaxf(p1[1] + q1[1], 0.f));
            un.u[3] = pkbf(fmaxf(p1[2] + q1[2], 0.f), fmaxf(p1[3] + q1[3], 0.f));
            h1f[nt][ks] = un.v;
        }
    }

    // ---- phases 3-5 fused, kappa-chunked: GEMM2(swapped) -> pack -> 2KB LDS -> GEMM3 ----
    unsigned char* Ck = Cks + w * 2048;
    f32x4 acc3[2];
    acc3[0] = zero4; acc3[1] = zero4;
    #pragma unroll 1
    for (int ks = 0; ks < 4; ++ks) {
        f32x4 a2[2][2];
        a2[0][0] = zero4; a2[0][1] = zero4; a2[1][0] = zero4; a2[1][1] = zero4;
        #pragma unroll
        for (int ksp = 0; ksp < 4; ++ksp) {
            #pragma unroll
            for (int mt1 = 0; mt1 < 2; ++mt1) {
                const bf16x8 wf = *(const bf16x8*)(W2f + (((2 * ks + mt1) * 4 + ksp) * 64 + l) * 8);
                a2[mt1][0] = __builtin_amdgcn_mfma_f32_16x16x32_bf16(wf, h1f[0][ksp], a2[mt1][0], 0, 0, 0);
                a2[mt1][1] = __builtin_amdgcn_mfma_f32_16x16x32_bf16(wf, h1f[1][ksp], a2[mt1][1], 0, 0, 0);
            }
        }
        // pack (bias+relu) and write chunk (kappa-local = 16*mt1 + 4g + r)
        #pragma unroll
        for (int mt1 = 0; mt1 < 2; ++mt1) {
            const f32x4 bv = *(const f32x4*)(b2 + 32 * ks + 16 * mt1 + 4 * g);
            #pragma unroll
            for (int nt = 0; nt < 2; ++nt) {
                const int p = c + 16 * nt;
                uint2 pk2;
                pk2.x = pkbf(fmaxf(a2[mt1][nt][0] + bv[0], 0.f), fmaxf(a2[mt1][nt][1] + bv[1], 0.f));
                pk2.y = pkbf(fmaxf(a2[mt1][nt][2] + bv[2], 0.f), fmaxf(a2[mt1][nt][3] + bv[3], 0.f));
                *(uint2*)(Ck + ((p * 64 + 32 * mt1 + 8 * g) ^ (((p >> 1) & 3) << 4))) = pk2;
            }
        }
        // GEMM3 partial: A = H2 chunk (self-symmetric frag), B = W3f[ks]
        const bf16x8 w3 = *(const bf16x8*)(W3f + (ks * 64 + l) * 8);
        #pragma unroll
        for (int nt = 0; nt < 2; ++nt) {
            const int p = c + 16 * nt;
            const bf16x8 ha = *(const bf16x8*)(Ck + ((p * 64 + 16 * g) ^ (((p >> 1) & 3) << 4)));
            acc3[nt] = __builtin_amdgcn_mfma_f32_16x16x32_bf16(ha, w3, acc3[nt], 0, 0, 0);
        }
    }

    // ---- phase 6: mask diagonal (j = 4g+r), sum over j, accumulate into out ----
    const float b3v = (c < 6) ? b3[c] : 0.f;
    #pragma unroll
    for (int nt = 0; nt < 2; ++nt) {
        const int i = i0 + nt;
        float s = 0.f;
        #pragma unroll
        for (int r = 0; r < 4; ++r) {
            const int j = 4 * g + r;
            if (j != i) s += acc3[nt][r] + b3v;
        }
        s += __shfl_xor(s, 16, 64);
        s += __shfl_xor(s, 32, 64);
        if (g == 0 && c < 6) out[b * 96 + i * 6 + c] += s;
    }
}

extern "C" void kernel_launch(void* const* d_in, const int* in_sizes, int n_in,
                              void* d_out, int out_size, void* d_ws, size_t ws_size,
                              hipStream_t stream) {
    const float* config = (const float*)d_in[0];
    const float* action = (const float*)d_in[1];
    const float* uW1 = (const float*)d_in[2];
    const float* ub1 = (const float*)d_in[3];
    const float* uW2 = (const float*)d_in[4];
    const float* ub2 = (const float*)d_in[5];
    const float* uW3 = (const float*)d_in[6];
    const float* ub3 = (const float*)d_in[7];
    const float* bW1 = (const float*)d_in[8];
    const float* bb1 = (const float*)d_in[9];
    const float* bW2 = (const float*)d_in[10];
    const float* bb2 = (const float*)d_in[11];
    const float* bW3 = (const float*)d_in[12];
    const float* bb3 = (const float*)d_in[13];
    float* out = (float*)d_out;

    unsigned short* ws   = (unsigned short*)d_ws;
    unsigned short* uW1f = ws;            // 8192 elems
    unsigned short* bW1f = ws + 8192;     // 8192
    unsigned short* uW2f = ws + 16384;    // 16384
    unsigned short* bW2f = ws + 32768;    // 16384
    unsigned short* uW3f = ws + 49152;    // 2048
    unsigned short* bW3f = ws + 51200;    // 2048

    prep_all<<<208, 256, 0, stream>>>(uW1, uW2, uW3, bW1, bW2, bW3, ws);
    // unary first: writes out = objs + u_out (every element exactly once)
    unary_kernel<<<512, 256, 0, stream>>>(config, action, uW1f, ub1, uW2f, ub2, uW3f, ub3, out);
    // binary second: out += b_sum (stream-ordered after unary)
    binary_kernel<<<8192, 256, 0, stream>>>(config, action, bW1f, bb1, bW2f, bb2, bW3f, bb3, out);
}